// Round 2
// baseline (172.441 us; speedup 1.0000x reference)
//
#include <hip/hip_runtime.h>

typedef unsigned short u16;
typedef unsigned int   u32;

typedef __attribute__((ext_vector_type(4))) float  f32x4;
typedef __attribute__((ext_vector_type(4))) u32    u32x4;
typedef __attribute__((ext_vector_type(8))) __bf16 bf16x8;

#define B_  2
#define L_  2048
#define H_  16

// ---------- bf16 helpers ----------
__device__ static inline u16 f2bf(float f) {
  u32 u = __builtin_bit_cast(u32, f);
  u32 r = u + 0x7fffu + ((u >> 16) & 1u);
  return (u16)(r >> 16);
}
__device__ static inline u32 pack2(float a, float b) {   // RTNE pair pack
  return (u32)f2bf(a) | ((u32)f2bf(b) << 16);
}
// one-instruction truncating pair pack: dst = {hi16(b), hi16(a)} via v_perm_b32
__device__ static inline u32 pack2t(float a, float b) {
  return __builtin_amdgcn_perm(__builtin_bit_cast(u32, b),
                               __builtin_bit_cast(u32, a), 0x07060302u);
}

// permlane swaps (gfx950): a' = {a.lo32, b.lo32}, b' = {a.hi32, b.hi32}
__device__ static inline void swap32p(u32& a, u32& b) {
  auto r = __builtin_amdgcn_permlane32_swap(a, b, false, false);
  a = r[0]; b = r[1];
}
// a' = {a.r0, b.r0, a.r2, b.r2}, b' = {a.r1, b.r1, a.r3, b.r3} (16-lane rows)
__device__ static inline void swap16p(u32& a, u32& b) {
  auto r = __builtin_amdgcn_permlane16_swap(a, b, false, false);
  a = r[0]; b = r[1];
}

// async global->LDS, 16B/lane. LDS dest = wave-uniform base + lane*16.
__device__ static inline void gload_lds16(const u16* g, u16* lds) {
  __builtin_amdgcn_global_load_lds((__attribute__((address_space(1))) void*)(g),
                                   (__attribute__((address_space(3))) void*)(lds),
                                   16, 0, 0);
}

// ---------------------------------------------------------------------------
// fused fp32 -> bf16 pack for x, Wqkv, Wo (RTNE — GEMM inputs keep accuracy).
// softmax 1/sqrt(dk)=0.125 folded into W_q rows (power-of-2: bit-identical P).
// ---------------------------------------------------------------------------
__global__ __launch_bounds__(256) void cvt3_kernel(
    const float4* __restrict__ a, uint2* __restrict__ ao, int na,
    const float4* __restrict__ b, uint2* __restrict__ bo, int nb,
    const float4* __restrict__ c, uint2* __restrict__ co, int nc)
{
  const int step = gridDim.x * 256;
  constexpr int nq = 1024 * 1024 / 4;          // float4 count of the W_q rows
  for (int i = blockIdx.x * 256 + threadIdx.x; i < na; i += step) {
    float4 f = a[i];
    ao[i] = make_uint2(pack2(f.x, f.y), pack2(f.z, f.w));
  }
  for (int i = blockIdx.x * 256 + threadIdx.x; i < nb; i += step) {
    float4 f = b[i];
    const float s = (i < nq) ? 0.125f : 1.0f;
    bo[i] = make_uint2(pack2(f.x * s, f.y * s), pack2(f.z * s, f.w * s));
  }
  for (int i = blockIdx.x * 256 + threadIdx.x; i < nc; i += step) {
    float4 f = c[i];
    co[i] = make_uint2(pack2(f.x, f.y), pack2(f.z, f.w));
  }
}

// ---------------------------------------------------------------------------
// GEMM: C[M,N] = A[M,K] @ Bt[N,K]^T, bf16 in, fp32 MFMA accumulate.
// m97 structure + source-permuted XOR chunk swizzle (R6). Unchanged.
// ---------------------------------------------------------------------------
template <bool OUT_F32, int NT, bool DBUF>
__global__ __launch_bounds__(256) void gemm_bt_kernel(
    const u16* __restrict__ A, const u16* __restrict__ Bt, void* __restrict__ Cv,
    const int K, const int N)
{
  constexpr int NB = DBUF ? 2 : 1;
  constexpr int JT = NT / 32;                    // j-tiles per wave
  __shared__ __attribute__((aligned(16))) u16 Al[NB][128 * 64];
  __shared__ __attribute__((aligned(16))) u16 Bl[NB][NT * 64];

  const int tid  = threadIdx.x;
  const int w    = tid >> 6;
  const int lane = tid & 63;
  const int m0 = blockIdx.y * 128;
  const int n0 = blockIdx.x * NT;
  const int mo = (w >> 1) * 64;
  const int no = (w & 1) * (NT / 2);

  const int sr8  = lane >> 3;                    // staging row-in-group
  const int scol = (((lane & 7) ^ ((lane >> 3) & 7)) * 8);   // swizzled source chunk

  const f32x4 zero = {0.f, 0.f, 0.f, 0.f};
  f32x4 acc[4][JT];
  #pragma unroll
  for (int i = 0; i < 4; ++i)
    #pragma unroll
    for (int j = 0; j < JT; ++j) acc[i][j] = zero;

  const int frow = lane & 15;
  const int fg   = lane >> 4;

  auto stage = [&](int buf, int k0) {
    #pragma unroll
    for (int inst = 0; inst < 4; ++inst) {
      const int r = w * 32 + inst * 8 + sr8;
      gload_lds16(A + (size_t)(m0 + r) * K + k0 + scol, &Al[buf][(w * 32 + inst * 8) * 64]);
    }
    #pragma unroll
    for (int inst = 0; inst < NT / 32; ++inst) {
      const int r = w * (NT / 4) + inst * 8 + sr8;
      gload_lds16(Bt + (size_t)(n0 + r) * K + k0 + scol, &Bl[buf][(w * (NT / 4) + inst * 8) * 64]);
    }
  };

  if (DBUF) stage(0, 0);

  int cur = 0;
  for (int k0 = 0; k0 < K; k0 += 64) {
    __syncthreads();
    if (DBUF) {
      if (k0 + 64 < K) stage(cur ^ 1, k0 + 64);
    } else {
      stage(0, k0);
      __syncthreads();
    }
    #pragma unroll
    for (int ks = 0; ks < 2; ++ks) {
      const int fco = ((ks * 4 + fg) ^ (frow & 7)) * 8;      // swizzled read chunk
      bf16x8 af[4], bfr[JT];
      #pragma unroll
      for (int i = 0; i < 4; ++i)
        af[i] = *(const bf16x8*)&Al[cur][(mo + i * 16 + frow) * 64 + fco];
      #pragma unroll
      for (int j = 0; j < JT; ++j)
        bfr[j] = *(const bf16x8*)&Bl[cur][(no + j * 16 + frow) * 64 + fco];
      #pragma unroll
      for (int i = 0; i < 4; ++i)
        #pragma unroll
        for (int j = 0; j < JT; ++j)
          acc[i][j] = __builtin_amdgcn_mfma_f32_16x16x32_bf16(af[i], bfr[j], acc[i][j], 0, 0, 0);
    }
    if (DBUF) cur ^= 1;
  }

  const int crow0 = m0 + mo + (lane >> 4) * 4;
  const int ccol0 = n0 + no + (lane & 15);
  #pragma unroll
  for (int i = 0; i < 4; ++i)
    #pragma unroll
    for (int j = 0; j < JT; ++j)
      #pragma unroll
      for (int r = 0; r < 4; ++r) {
        const size_t idx = (size_t)(crow0 + i * 16 + r) * N + (ccol0 + j * 16);
        if (OUT_F32) ((float*)Cv)[idx] = acc[i][j][r];
        else         ((u16*)Cv)[idx]   = f2bf(acc[i][j][r]);
      }
}

// ---------------------------------------------------------------------------
// MFMA causal flash attention — R11: LDS-traffic restructure.
// Theory: R10 was LDS-read-pipe-bound (288 ds_read_b128/phase-round x 12cyc
// = 3456 cyc = measured phase time). Fix:
//  * 32 q-rows per WAVE (was 16): each K/V fragment read feeds 2 q-column
//    fragments -> K/V LDS reads per FLOP halved.
//  * 128-thread blocks (2 waves), 64-q chunks, grid (32 bh, 32) = 1024 blocks,
//    32 KiB LDS -> 4 blocks/CU resident. Same CU-sum balance remap.
//  * P^T never touches LDS: producer->consumer k-redistribution done
//    in-register with permlane32_swap + permlane16_swap (verified equivalent
//    to R10's swizzled PTd round-trip: position algebra kp ^ 4*(fr&7)).
// Per block-phase LDS reads: 72 -> 32 b128; writes also shrink (no P).
// ---------------------------------------------------------------------------
__global__ __launch_bounds__(128) void attn_mfma_kernel(const u16* __restrict__ qkv,
                                                        u16* __restrict__ y)
{
  __shared__ __attribute__((aligned(16))) unsigned char smem[32768];

  const int tid  = threadIdx.x;
  const int w    = tid >> 6;                   // wave 0/1
  const int lane = tid & 63;
  const int fr   = lane & 15;
  const int fg   = lane >> 4;
  const int bh   = blockIdx.x;                 // bh on x => XCD affinity
  const int bb   = bh >> 4;
  const int hh   = bh & 15;
  const size_t rb = (size_t)bb * L_;

  // load-balance remap: blocks at id, id+256, id+512, id+768 (same CU under
  // round-robin dispatch) get qt = {a, 31-a, 8+a, 23-a} -> 66 tiles total.
  const int a  = blockIdx.y & 7;
  const int cc = blockIdx.y >> 3;
  const int qt = (cc == 0) ? a : (cc == 1) ? (31 - a) : (cc == 2) ? (8 + a) : (23 - a);

  u16* Kt  = (u16*)(smem);                     // [buf*4096 + row*64 + col] bf16
  u32* Vtd = (u32*)(smem + 16384);             // [buf*2048 + d*32 + kp] u32

  // V staging: thread handles key-pair column kkp, d-rows 16*dc .. 16*dc+15
  const int kkp = tid & 31;
  const int dc  = tid >> 5;                    // 0..3

  // K staging (R6 swizzle): wave w stages rows [32w, 32w+32)
  const int ksr  = lane >> 3;
  const int ksc  = (((lane & 7) ^ ((lane >> 3) & 7)) * 8);
  const int kco0 = ((fg) ^ (fr & 7)) * 8;
  const int kco1 = ((4 + fg) ^ (fr & 7)) * 8;
  // swizzled chunk offsets for Vtd reads (dwords)
  const int cro0 = 4 * ((fg) ^ (fr & 7));
  const int cro1 = 4 * ((4 + fg) ^ (fr & 7));

  const int q0 = qt * 64;
  const int qw = q0 + w * 32;                  // wave's first q row
  const int n  = qt + 1;                       // k-tiles for this chunk

  // Q fragments (B-operand of S^T), 2 q-column frags x 2 d-halves.
  // W_q pre-scaled by 0.125.
  const bf16x8 qf00 = *(const bf16x8*)(qkv + (rb + qw + fr) * 3072 + hh * 64 + fg * 8);
  const bf16x8 qf01 = *(const bf16x8*)(qkv + (rb + qw + fr) * 3072 + hh * 64 + 32 + fg * 8);
  const bf16x8 qf10 = *(const bf16x8*)(qkv + (rb + qw + 16 + fr) * 3072 + hh * 64 + fg * 8);
  const bf16x8 qf11 = *(const bf16x8*)(qkv + (rb + qw + 16 + fr) * 3072 + hh * 64 + 32 + fg * 8);

  const f32x4 zero = {0.f, 0.f, 0.f, 0.f};
  f32x4 oacc[4][2];
  #pragma unroll
  for (int mt = 0; mt < 4; ++mt) {
    oacc[mt][0] = zero;
    oacc[mt][1] = zero;
  }
  float ls0 = 0.f, ls1 = 0.f;

  auto stageK = [&](int buf, int kt) {
    #pragma unroll
    for (int i = 0; i < 4; ++i)
      gload_lds16(qkv + (rb + kt + w * 32 + i * 8 + ksr) * 3072 + 1024 + hh * 64 + ksc,
                  &Kt[buf * 4096 + (w * 32 + i * 8) * 64]);
  };
  auto loadV = [&](int kt, uint4* va) {
    const u16* vp = qkv + (rb + kt + 2 * kkp) * 3072 + 2048 + hh * 64 + dc * 16;
    va[0] = *(const uint4*)(vp);
    va[1] = *(const uint4*)(vp + 8);
    va[2] = *(const uint4*)(vp + 3072);
    va[3] = *(const uint4*)(vp + 3072 + 8);
  };
  auto writeV = [&](int buf, const uint4* va) {
    u16 a16[16], b16[16];
    *(uint4*)(a16)     = va[0]; *(uint4*)(a16 + 8) = va[1];
    *(uint4*)(b16)     = va[2]; *(uint4*)(b16 + 8) = va[3];
    #pragma unroll
    for (int i = 0; i < 16; ++i) {
      const int d = dc * 16 + i;
      Vtd[buf * 2048 + d * 32 + 4 * ((kkp >> 2) ^ (i & 7)) + (kkp & 3)] =
          (u32)a16[i] | ((u32)b16[i] << 16);
    }
  };

  // ---- prologue: stage tile 0 into buffer 0 ----
  {
    stageK(0, 0);
    uint4 va[4];
    loadV(0, va);
    writeV(0, va);
  }

  int cur = 0;
  for (int it = 0; it < n; ++it) {
    __syncthreads();   // publishes K/V[cur]

    const int  kt       = it * 64;
    const bool havenext = (it + 1) < n;
    uint4 va[4];
    if (havenext) {
      stageK(cur ^ 1, kt + 64);
      loadV(kt + 64, va);
    }

    // S^T = K Q^T : sacc[nt][qc][r] = S[q = qw + qc*16 + fr][k = kt + nt*16 + 4fg + r]
    f32x4 sacc[4][2];
    #pragma unroll
    for (int nt = 0; nt < 4; ++nt) { sacc[nt][0] = zero; sacc[nt][1] = zero; }
    __builtin_amdgcn_s_setprio(1);
    #pragma unroll
    for (int nt = 0; nt < 4; ++nt) {
      bf16x8 kf0 = *(const bf16x8*)&Kt[cur * 4096 + (nt * 16 + fr) * 64 + kco0];
      bf16x8 kf1 = *(const bf16x8*)&Kt[cur * 4096 + (nt * 16 + fr) * 64 + kco1];
      sacc[nt][0] = __builtin_amdgcn_mfma_f32_16x16x32_bf16(kf0, qf00, sacc[nt][0], 0, 0, 0);
      sacc[nt][0] = __builtin_amdgcn_mfma_f32_16x16x32_bf16(kf1, qf01, sacc[nt][0], 0, 0, 0);
      sacc[nt][1] = __builtin_amdgcn_mfma_f32_16x16x32_bf16(kf0, qf10, sacc[nt][1], 0, 0, 0);
      sacc[nt][1] = __builtin_amdgcn_mfma_f32_16x16x32_bf16(kf1, qf11, sacc[nt][1], 0, 0, 0);
    }
    __builtin_amdgcn_s_setprio(0);

    // p = exp(s); mask on diagonal tile; pack to bf16 pairs in-register.
    // pk[nt][qc][h] covers k-pair kp = 8nt + 2fg + h (q = qc*16 + fr).
    u32 pk[4][2][2];
    if (kt == q0) {
      #pragma unroll
      for (int nt = 0; nt < 4; ++nt)
        #pragma unroll
        for (int qc = 0; qc < 2; ++qc) {
          float p[4];
          #pragma unroll
          for (int r = 0; r < 4; ++r) {
            p[r] = (nt * 16 + 4 * fg + r > w * 32 + qc * 16 + fr)
                       ? 0.f : __expf(sacc[nt][qc][r]);
            if (qc == 0) ls0 += p[r]; else ls1 += p[r];
          }
          pk[nt][qc][0] = pack2t(p[0], p[1]);
          pk[nt][qc][1] = pack2t(p[2], p[3]);
        }
    } else {
      #pragma unroll
      for (int nt = 0; nt < 4; ++nt)
        #pragma unroll
        for (int qc = 0; qc < 2; ++qc) {
          float p[4];
          #pragma unroll
          for (int r = 0; r < 4; ++r) {
            p[r] = __expf(sacc[nt][qc][r]);
            if (qc == 0) ls0 += p[r]; else ls1 += p[r];
          }
          pk[nt][qc][0] = pack2t(p[0], p[1]);
          pk[nt][qc][1] = pack2t(p[2], p[3]);
        }
    }

    // O^T += V^T P^T. P^T B-frag built in-register:
    // target lane (fr,fg') needs k-pairs 16ks+4fg'+t -> permlane32+16 swaps.
    __builtin_amdgcn_s_setprio(1);
    #pragma unroll
    for (int ks = 0; ks < 2; ++ks) {
      bf16x8 pf[2];
      #pragma unroll
      for (int qc = 0; qc < 2; ++qc) {
        u32 P0 = pk[2 * ks][qc][0], Q0 = pk[2 * ks + 1][qc][0];
        u32 P1 = pk[2 * ks][qc][1], Q1 = pk[2 * ks + 1][qc][1];
        swap32p(P0, Q0);           // P = {X.lo, Y.lo}, Q = {X.hi, Y.hi}
        swap32p(P1, Q1);
        swap16p(P0, Q0);           // P = R (even src fg), Q = S (odd src fg)
        swap16p(P1, Q1);
        pf[qc] = __builtin_bit_cast(bf16x8, (u32x4){P0, P1, Q0, Q1});
      }
      const int cro = ks ? cro1 : cro0;
      #pragma unroll
      for (int mt = 0; mt < 4; ++mt) {
        bf16x8 vf = *(const bf16x8*)&Vtd[cur * 2048 + (mt * 16 + fr) * 32 + cro];
        oacc[mt][0] = __builtin_amdgcn_mfma_f32_16x16x32_bf16(vf, pf[0], oacc[mt][0], 0, 0, 0);
        oacc[mt][1] = __builtin_amdgcn_mfma_f32_16x16x32_bf16(vf, pf[1], oacc[mt][1], 0, 0, 0);
      }
    }
    __builtin_amdgcn_s_setprio(0);

    if (havenext) writeV(cur ^ 1, va);
    cur ^= 1;
  }

  // reduce l over the 4 fg lanes sharing each q row
  ls0 += __shfl_xor(ls0, 16);
  ls0 += __shfl_xor(ls0, 32);
  ls1 += __shfl_xor(ls1, 16);
  ls1 += __shfl_xor(ls1, 32);
  const float inv0 = 1.f / ls0;
  const float inv1 = 1.f / ls1;

  u16* yp0 = y + (rb + qw + fr) * 1024 + hh * 64 + 4 * fg;
  u16* yp1 = y + (rb + qw + 16 + fr) * 1024 + hh * 64 + 4 * fg;
  #pragma unroll
  for (int mt = 0; mt < 4; ++mt) {
    f32x4 o0 = oacc[mt][0];
    f32x4 o1 = oacc[mt][1];
    *(uint2*)(yp0 + mt * 16) = make_uint2(pack2(o0[0] * inv0, o0[1] * inv0),
                                          pack2(o0[2] * inv0, o0[3] * inv0));
    *(uint2*)(yp1 + mt * 16) = make_uint2(pack2(o1[0] * inv1, o1[1] * inv1),
                                          pack2(o1[2] * inv1, o1[3] * inv1));
  }
}

// ---------------------------------------------------------------------------
extern "C" void kernel_launch(void* const* d_in, const int* in_sizes, int n_in,
                              void* d_out, int out_size, void* d_ws, size_t ws_size,
                              hipStream_t stream)
{
  const float* x    = (const float*)d_in[0];   // [B*L, 1024] fp32
  const float* Wqkv = (const float*)d_in[1];   // [3072, 1024] fp32
  const float* Wo   = (const float*)d_in[2];   // [1024, 1024] fp32
  float* out = (float*)d_out;                  // [B*L, 1024] fp32

  u16* xb    = (u16*)d_ws;                      // [4096,1024]  8 MiB
  u16* Wqkvb = xb    + (size_t)4096 * 1024;     // [3072,1024]  6 MiB
  u16* Wob   = Wqkvb + (size_t)3072 * 1024;     // [1024,1024]  2 MiB
  u16* qkv   = Wob   + (size_t)1024 * 1024;     // [4096,3072] 24 MiB
  u16* y     = qkv   + (size_t)4096 * 3072;     // [4096,1024]  8 MiB

  cvt3_kernel<<<dim3(2048), dim3(256), 0, stream>>>(
      (const float4*)x,    (uint2*)xb,    4096 * 1024 / 4,
      (const float4*)Wqkv, (uint2*)Wqkvb, 3072 * 1024 / 4,
      (const float4*)Wo,   (uint2*)Wob,   1024 * 1024 / 4);

  // qkv = x @ Wqkv^T   (M=4096, N=3072, K=1024)  [R6 config, unchanged]
  gemm_bt_kernel<false, 128, false><<<dim3(3072 / 128, 4096 / 128), dim3(256), 0, stream>>>(
      xb, Wqkvb, qkv, 1024, 3072);
  // causal MHA -> y [4096, 1024] bf16  (R11: 128-thr blocks, 32q/wave, reg-P)
  attn_mfma_kernel<<<dim3(B_ * H_, 32), dim3(128), 0, stream>>>(qkv, y);
  // out = y @ Wo^T     (M=4096, N=1024, K=1024), fp32 out
  gemm_bt_kernel<true, 64, true><<<dim3(1024 / 64, 4096 / 128), dim3(256), 0, stream>>>(
      y, Wob, out, 1024, 1024);
}

// Round 3
// 159.166 us; speedup vs baseline: 1.0834x; 1.0834x over previous
//
#include <hip/hip_runtime.h>

typedef unsigned short u16;
typedef unsigned int   u32;

typedef __attribute__((ext_vector_type(4)))  float  f32x4;
typedef __attribute__((ext_vector_type(16))) float  f32x16;
typedef __attribute__((ext_vector_type(4)))  u32    u32x4;
typedef __attribute__((ext_vector_type(8)))  __bf16 bf16x8;

#define B_  2
#define L_  2048
#define H_  16

// ---------- bf16 helpers ----------
__device__ static inline u16 f2bf(float f) {
  u32 u = __builtin_bit_cast(u32, f);
  u32 r = u + 0x7fffu + ((u >> 16) & 1u);
  return (u16)(r >> 16);
}
__device__ static inline u32 pack2(float a, float b) {   // RTNE pair pack
  return (u32)f2bf(a) | ((u32)f2bf(b) << 16);
}
// one-instruction truncating pair pack: dst = {hi16(b), hi16(a)} via v_perm_b32
__device__ static inline u32 pack2t(float a, float b) {
  return __builtin_amdgcn_perm(__builtin_bit_cast(u32, b),
                               __builtin_bit_cast(u32, a), 0x07060302u);
}

// permlane32_swap: a' = {a.lo32lanes, b.lo32lanes}, b' = {a.hi32lanes, b.hi32lanes}
__device__ static inline void swap32p(u32& a, u32& b) {
  auto r = __builtin_amdgcn_permlane32_swap(a, b, false, false);
  a = r[0]; b = r[1];
}

// async global->LDS, 16B/lane. LDS dest = wave-uniform base + lane*16.
__device__ static inline void gload_lds16(const u16* g, u16* lds) {
  __builtin_amdgcn_global_load_lds((__attribute__((address_space(1))) void*)(g),
                                   (__attribute__((address_space(3))) void*)(lds),
                                   16, 0, 0);
}

// ---------------------------------------------------------------------------
// fused fp32 -> bf16 pack for x, Wqkv, Wo (RTNE — GEMM inputs keep accuracy).
// softmax 1/sqrt(dk)=0.125 folded into W_q rows (power-of-2: bit-identical P).
// ---------------------------------------------------------------------------
__global__ __launch_bounds__(256) void cvt3_kernel(
    const float4* __restrict__ a, uint2* __restrict__ ao, int na,
    const float4* __restrict__ b, uint2* __restrict__ bo, int nb,
    const float4* __restrict__ c, uint2* __restrict__ co, int nc)
{
  const int step = gridDim.x * 256;
  constexpr int nq = 1024 * 1024 / 4;          // float4 count of the W_q rows
  for (int i = blockIdx.x * 256 + threadIdx.x; i < na; i += step) {
    float4 f = a[i];
    ao[i] = make_uint2(pack2(f.x, f.y), pack2(f.z, f.w));
  }
  for (int i = blockIdx.x * 256 + threadIdx.x; i < nb; i += step) {
    float4 f = b[i];
    const float s = (i < nq) ? 0.125f : 1.0f;
    bo[i] = make_uint2(pack2(f.x * s, f.y * s), pack2(f.z * s, f.w * s));
  }
  for (int i = blockIdx.x * 256 + threadIdx.x; i < nc; i += step) {
    float4 f = c[i];
    co[i] = make_uint2(pack2(f.x, f.y), pack2(f.z, f.w));
  }
}

// ---------------------------------------------------------------------------
// GEMM: C[M,N] = A[M,K] @ Bt[N,K]^T, bf16 in, fp32 MFMA accumulate.
// m97 structure + source-permuted XOR chunk swizzle (R6). Unchanged.
// ---------------------------------------------------------------------------
template <bool OUT_F32, int NT, bool DBUF>
__global__ __launch_bounds__(256) void gemm_bt_kernel(
    const u16* __restrict__ A, const u16* __restrict__ Bt, void* __restrict__ Cv,
    const int K, const int N)
{
  constexpr int NB = DBUF ? 2 : 1;
  constexpr int JT = NT / 32;                    // j-tiles per wave
  __shared__ __attribute__((aligned(16))) u16 Al[NB][128 * 64];
  __shared__ __attribute__((aligned(16))) u16 Bl[NB][NT * 64];

  const int tid  = threadIdx.x;
  const int w    = tid >> 6;
  const int lane = tid & 63;
  const int m0 = blockIdx.y * 128;
  const int n0 = blockIdx.x * NT;
  const int mo = (w >> 1) * 64;
  const int no = (w & 1) * (NT / 2);

  const int sr8  = lane >> 3;                    // staging row-in-group
  const int scol = (((lane & 7) ^ ((lane >> 3) & 7)) * 8);   // swizzled source chunk

  const f32x4 zero = {0.f, 0.f, 0.f, 0.f};
  f32x4 acc[4][JT];
  #pragma unroll
  for (int i = 0; i < 4; ++i)
    #pragma unroll
    for (int j = 0; j < JT; ++j) acc[i][j] = zero;

  const int frow = lane & 15;
  const int fg   = lane >> 4;

  auto stage = [&](int buf, int k0) {
    #pragma unroll
    for (int inst = 0; inst < 4; ++inst) {
      const int r = w * 32 + inst * 8 + sr8;
      gload_lds16(A + (size_t)(m0 + r) * K + k0 + scol, &Al[buf][(w * 32 + inst * 8) * 64]);
    }
    #pragma unroll
    for (int inst = 0; inst < NT / 32; ++inst) {
      const int r = w * (NT / 4) + inst * 8 + sr8;
      gload_lds16(Bt + (size_t)(n0 + r) * K + k0 + scol, &Bl[buf][(w * (NT / 4) + inst * 8) * 64]);
    }
  };

  if (DBUF) stage(0, 0);

  int cur = 0;
  for (int k0 = 0; k0 < K; k0 += 64) {
    __syncthreads();
    if (DBUF) {
      if (k0 + 64 < K) stage(cur ^ 1, k0 + 64);
    } else {
      stage(0, k0);
      __syncthreads();
    }
    #pragma unroll
    for (int ks = 0; ks < 2; ++ks) {
      const int fco = ((ks * 4 + fg) ^ (frow & 7)) * 8;      // swizzled read chunk
      bf16x8 af[4], bfr[JT];
      #pragma unroll
      for (int i = 0; i < 4; ++i)
        af[i] = *(const bf16x8*)&Al[cur][(mo + i * 16 + frow) * 64 + fco];
      #pragma unroll
      for (int j = 0; j < JT; ++j)
        bfr[j] = *(const bf16x8*)&Bl[cur][(no + j * 16 + frow) * 64 + fco];
      #pragma unroll
      for (int i = 0; i < 4; ++i)
        #pragma unroll
        for (int j = 0; j < JT; ++j)
          acc[i][j] = __builtin_amdgcn_mfma_f32_16x16x32_bf16(af[i], bfr[j], acc[i][j], 0, 0, 0);
    }
    if (DBUF) cur ^= 1;
  }

  const int crow0 = m0 + mo + (lane >> 4) * 4;
  const int ccol0 = n0 + no + (lane & 15);
  #pragma unroll
  for (int i = 0; i < 4; ++i)
    #pragma unroll
    for (int j = 0; j < JT; ++j)
      #pragma unroll
      for (int r = 0; r < 4; ++r) {
        const size_t idx = (size_t)(crow0 + i * 16 + r) * N + (ccol0 + j * 16);
        if (OUT_F32) ((float*)Cv)[idx] = acc[i][j][r];
        else         ((u16*)Cv)[idx]   = f2bf(acc[i][j][r]);
      }
}

// ---------------------------------------------------------------------------
// MFMA causal flash attention — R12: 32x32 MFMA shape switch.
// Lesson R9/R10/R11: perf tracks waves/CU (16 -> 46us, 8 -> 57us); latency-
// bound, TLP is king. So keep R10's block geometry (256 thr, 64-q tile, grid
// 1024 = 4 blocks/CU, 16 waves/CU, 32 KiB LDS) and cut LDS-ops/FLOP by
// switching to mfma_f32_32x32x16_bf16:
//  * wave (qh=w>>1, kh=w&1) computes q-half x k-half of the 64x64 tile
//  * 32x32 MFMA: same operand bytes/lane, 2x FLOPs -> K/V b128 reads per
//    block-phase halve (64 -> 32)
//  * P in-register: S^T acc (col=lane&31=q, row=(reg&3)+8(reg>>2)+4hi=k)
//    -> PV B-frag via 2 permlane32_swap per 16-k step (4/phase)
//  * k-half partials (O, l) combine once at the end via 16 KiB LDS overlay
//  * diag tile: wave (qh=0,kh=1) fully masked -> skipped
// ---------------------------------------------------------------------------
__global__ __launch_bounds__(256, 4) void attn_mfma_kernel(const u16* __restrict__ qkv,
                                                           u16* __restrict__ y)
{
  __shared__ __attribute__((aligned(16))) unsigned char smem[32768];

  const int tid  = threadIdx.x;
  const int w    = tid >> 6;                   // wave 0..3
  const int lane = tid & 63;
  const int ql   = lane & 31;                  // q-col (also d-row / k-row index)
  const int hi   = lane >> 5;
  const int qh   = w >> 1;                     // q-half of the 64-q tile
  const int kh   = w & 1;                      // k-half split
  const int bh   = blockIdx.x;                 // bh on x => XCD affinity
  const int bb   = bh >> 4;
  const int hh   = bh & 15;
  const size_t rb = (size_t)bb * L_;

  // load-balance remap: blocks at id, id+256, id+512, id+768 (same CU under
  // round-robin dispatch) get qt = {a, 31-a, 8+a, 23-a} -> 66 tiles total.
  const int a  = blockIdx.y & 7;
  const int cc = blockIdx.y >> 3;
  const int qt = (cc == 0) ? a : (cc == 1) ? (31 - a) : (cc == 2) ? (8 + a) : (23 - a);

  u16* Kt   = (u16*)(smem);                    // [buf*4096 + row*64 + col] bf16
  u32* Vtd  = (u32*)(smem + 16384);            // [buf*2048 + d*32 + kp] u32
  float* Ocmb = (float*)smem;                  // combine overlay [16][256] f32
  float* Lcmb = (float*)(smem + 16384);        // combine overlay [64] f32

  // V staging: thread handles key-pair column kkp, d-rows dc*8 .. dc*8+7
  const int kkp = lane & 31;
  const int dc  = 2 * w + (lane >> 5);         // 0..7

  // K staging (R6 swizzle): wave w stages rows w*16 .. w*16+15
  const int ksr = w * 16 + (lane >> 3);
  const int ksc = (((lane & 7) ^ ((lane >> 3) & 7)) * 8);

  const int q0 = qt * 64;
  const int qb = q0 + qh * 32;                 // wave's q-base; lane's q = qb+ql
  const int n  = qt + 1;                       // k-tiles for this tile

  // Q B-frags (32x32x16): qf[s] = Q[qb+ql][d = 16s + 8hi .. +7], W_q pre-scaled
  bf16x8 qf[4];
  #pragma unroll
  for (int s = 0; s < 4; ++s)
    qf[s] = *(const bf16x8*)(qkv + (rb + qb + ql) * 3072 + hh * 64 + s * 16 + 8 * hi);

  f32x16 oacc0 = {}, oacc1 = {};               // O^T d-tiles 0/1 (64 d x 32 q)
  float lsum = 0.f;

  auto stageK = [&](int buf, int kt) {
    #pragma unroll
    for (int inst = 0; inst < 2; ++inst)
      gload_lds16(qkv + (rb + kt + ksr + inst * 8) * 3072 + 1024 + hh * 64 + ksc,
                  &Kt[buf * 4096 + (w * 16 + inst * 8) * 64]);
  };
  auto loadV = [&](int kt, uint4& va, uint4& vb) {
    const u16* vp = qkv + (rb + kt + 2 * kkp) * 3072 + 2048 + hh * 64 + dc * 8;
    va = *(const uint4*)vp;
    vb = *(const uint4*)(vp + 3072);
  };
  auto writeV = [&](int buf, uint4 va, uint4 vb) {
    u16 a16[8], b16[8];
    *(uint4*)a16 = va; *(uint4*)b16 = vb;
    #pragma unroll
    for (int i = 0; i < 8; ++i)
      Vtd[buf * 2048 + (dc * 8 + i) * 32 + 4 * ((kkp >> 2) ^ i) + (kkp & 3)] =
          (u32)a16[i] | ((u32)b16[i] << 16);
  };

  // ---- prologue: stage tile 0 into buffer 0 ----
  {
    stageK(0, 0);
    uint4 va, vb;
    loadV(0, va, vb);
    writeV(0, va, vb);
  }

  int cur = 0;
  for (int it = 0; it < n; ++it) {
    __syncthreads();   // publishes K/V[cur]

    const int  kt       = it * 64;
    const bool havenext = (it + 1) < n;
    uint4 va, vb;
    if (havenext) {
      stageK(cur ^ 1, kt + 64);
      loadV(kt + 64, va, vb);
    }

    const bool diag = (kt == q0);
    if (!(diag && kh > qh)) {                  // (qh=0,kh=1) diag tile: all masked
      // S^T = K Q^T over this wave's k-half: 32q x 32k, chained over d (4x16)
      f32x16 sacc = {};
      __builtin_amdgcn_s_setprio(1);
      #pragma unroll
      for (int s = 0; s < 4; ++s) {
        bf16x8 kf = *(const bf16x8*)&Kt[cur * 4096 + (kh * 32 + ql) * 64 +
                                        (((2 * s + hi) ^ (ql & 7)) * 8)];
        sacc = __builtin_amdgcn_mfma_f32_32x32x16_bf16(kf, qf[s], sacc, 0, 0, 0);
      }
      __builtin_amdgcn_s_setprio(0);

      // p = exp(s); triangular mask only when kh==qh on the diag tile.
      // k-row(reg r) = (r&3) + 8*(r>>2) + 4*hi; pack pairs (rows 2j,2j+1).
      u32 u[8];
      if (diag && kh == qh) {
        #pragma unroll
        for (int j = 0; j < 8; ++j) {
          const int r0  = 2 * j;
          const int k0r = (r0 & 3) + 8 * (r0 >> 2) + 4 * hi;
          const float p0 = (k0r     > ql) ? 0.f : __expf(sacc[r0]);
          const float p1 = (k0r + 1 > ql) ? 0.f : __expf(sacc[r0 + 1]);
          lsum += p0 + p1;
          u[j] = pack2t(p0, p1);
        }
      } else {
        #pragma unroll
        for (int j = 0; j < 8; ++j) {
          const float p0 = __expf(sacc[2 * j]);
          const float p1 = __expf(sacc[2 * j + 1]);
          lsum += p0 + p1;
          u[j] = pack2t(p0, p1);
        }
      }

      // P^T B-frags in-register: swap k-row pair-groups across lane halves.
      swap32p(u[0], u[2]); swap32p(u[1], u[3]);      // ks=0: k-rows 8hi+0..7
      swap32p(u[4], u[6]); swap32p(u[5], u[7]);      // ks=1
      const bf16x8 pf0 = __builtin_bit_cast(bf16x8, (u32x4){u[0], u[1], u[2], u[3]});
      const bf16x8 pf1 = __builtin_bit_cast(bf16x8, (u32x4){u[4], u[5], u[6], u[7]});

      // O^T += V^T P^T (A = V^T[d 32-rows x 16 k], per d-tile, per 16-k step)
      __builtin_amdgcn_s_setprio(1);
      #pragma unroll
      for (int dt = 0; dt < 2; ++dt) {
        f32x16& oa = dt ? oacc1 : oacc0;
        const int d = dt * 32 + ql;
        bf16x8 vf0 = *(const bf16x8*)&Vtd[cur * 2048 + d * 32 + 4 * ((4 * kh + hi) ^ (ql & 7))];
        oa = __builtin_amdgcn_mfma_f32_32x32x16_bf16(vf0, pf0, oa, 0, 0, 0);
        bf16x8 vf1 = *(const bf16x8*)&Vtd[cur * 2048 + d * 32 + 4 * ((4 * kh + 2 + hi) ^ (ql & 7))];
        oa = __builtin_amdgcn_mfma_f32_32x32x16_bf16(vf1, pf1, oa, 0, 0, 0);
      }
      __builtin_amdgcn_s_setprio(0);
    }

    if (havenext) writeV(cur ^ 1, va, vb);
    cur ^= 1;
  }

  // l: combine the two hi-halves (each covers half the wave's k-rows)
  lsum += __shfl_xor(lsum, 32);

  // ---- combine the two k-half waves' partials (O = O0 + O1, l = l0 + l1) ----
  __syncthreads();   // all K/V LDS use done before overlaying combine area
  if (kh == 1) {
    #pragma unroll
    for (int dt = 0; dt < 2; ++dt)
      #pragma unroll
      for (int rq = 0; rq < 4; ++rq) {
        const f32x16& oa = dt ? oacc1 : oacc0;
        *(f32x4*)&Ocmb[(qh * 8 + dt * 4 + rq) * 256 + lane * 4] =
            (f32x4){oa[4 * rq], oa[4 * rq + 1], oa[4 * rq + 2], oa[4 * rq + 3]};
      }
    if (hi == 0) Lcmb[qh * 32 + ql] = lsum;
  }
  __syncthreads();
  if (kh == 0) {
    const float inv = 1.f / (lsum + Lcmb[qh * 32 + ql]);
    u16* yp = y + (rb + qb + ql) * 1024 + hh * 64;
    #pragma unroll
    for (int dt = 0; dt < 2; ++dt)
      #pragma unroll
      for (int rq = 0; rq < 4; ++rq) {
        const f32x16& oa = dt ? oacc1 : oacc0;
        const f32x4 oc = *(const f32x4*)&Ocmb[(qh * 8 + dt * 4 + rq) * 256 + lane * 4];
        const float v0 = (oa[4 * rq]     + oc[0]) * inv;
        const float v1 = (oa[4 * rq + 1] + oc[1]) * inv;
        const float v2 = (oa[4 * rq + 2] + oc[2]) * inv;
        const float v3 = (oa[4 * rq + 3] + oc[3]) * inv;
        // d = dt*32 + 8*rq + 4*hi + {0..3}
        *(uint2*)(yp + dt * 32 + 8 * rq + 4 * hi) = make_uint2(pack2(v0, v1), pack2(v2, v3));
      }
  }
}

// ---------------------------------------------------------------------------
extern "C" void kernel_launch(void* const* d_in, const int* in_sizes, int n_in,
                              void* d_out, int out_size, void* d_ws, size_t ws_size,
                              hipStream_t stream)
{
  const float* x    = (const float*)d_in[0];   // [B*L, 1024] fp32
  const float* Wqkv = (const float*)d_in[1];   // [3072, 1024] fp32
  const float* Wo   = (const float*)d_in[2];   // [1024, 1024] fp32
  float* out = (float*)d_out;                  // [B*L, 1024] fp32

  u16* xb    = (u16*)d_ws;                      // [4096,1024]  8 MiB
  u16* Wqkvb = xb    + (size_t)4096 * 1024;     // [3072,1024]  6 MiB
  u16* Wob   = Wqkvb + (size_t)3072 * 1024;     // [1024,1024]  2 MiB
  u16* qkv   = Wob   + (size_t)1024 * 1024;     // [4096,3072] 24 MiB
  u16* y     = qkv   + (size_t)4096 * 3072;     // [4096,1024]  8 MiB

  cvt3_kernel<<<dim3(2048), dim3(256), 0, stream>>>(
      (const float4*)x,    (uint2*)xb,    4096 * 1024 / 4,
      (const float4*)Wqkv, (uint2*)Wqkvb, 3072 * 1024 / 4,
      (const float4*)Wo,   (uint2*)Wob,   1024 * 1024 / 4);

  // qkv = x @ Wqkv^T   (M=4096, N=3072, K=1024)  [R6 config, unchanged]
  gemm_bt_kernel<false, 128, false><<<dim3(3072 / 128, 4096 / 128), dim3(256), 0, stream>>>(
      xb, Wqkvb, qkv, 1024, 3072);
  // causal MHA -> y [4096, 1024] bf16  (R12: 32x32 MFMA, 256 thr, 4 blk/CU)
  attn_mfma_kernel<<<dim3(B_ * H_, 32), dim3(256), 0, stream>>>(qkv, y);
  // out = y @ Wo^T     (M=4096, N=1024, K=1024), fp32 out
  gemm_bt_kernel<true, 64, true><<<dim3(1024 / 64, 4096 / 128), dim3(256), 0, stream>>>(
      y, Wob, out, 1024, 1024);
}